// Round 7
// baseline (449.995 us; speedup 1.0000x reference)
//
#include <hip/hip_runtime.h>
#include <math.h>

#define NB 16384
#define DD 1024
#define KF 5120   // concat feature K: uni(1024) + a_v,a_l,v_l(3*1024) + tri(1024)

typedef unsigned short u16;
typedef unsigned int u32;
typedef __attribute__((ext_vector_type(8))) short bf16x8;
typedef __attribute__((ext_vector_type(4))) float f32x4;

// ---------- helpers ----------
__device__ __forceinline__ float bf2f(u16 u){
  return __uint_as_float(((unsigned)u) << 16);
}
__device__ __forceinline__ u16 f2bf(float f){
  unsigned u = __float_as_uint(f);
  return (u16)((u + 0x7fffu + ((u >> 16) & 1u)) >> 16);   // RNE
}
__device__ __forceinline__ u16 f2bf_tr(float f){           // cheap truncate (MFMA inputs only)
  return (u16)(__float_as_uint(f) >> 16);
}
__device__ __forceinline__ u32 pack2bf(float a, float b){
  return (u32)f2bf(a) | ((u32)f2bf(b) << 16);
}
__device__ __forceinline__ float fast_tanh(float x){
  float e = __expf(2.0f * x);
  return 1.0f - 2.0f * __builtin_amdgcn_rcpf(e + 1.0f);
}
__device__ __forceinline__ float wredsum(float x){
  #pragma unroll
  for(int o = 32; o >= 1; o >>= 1) x += __shfl_xor(x, o);
  return x;
}
__device__ __forceinline__ float wredmax(float x){
  #pragma unroll
  for(int o = 32; o >= 1; o >>= 1) x = fmaxf(x, __shfl_xor(x, o));
  return x;
}
__device__ __forceinline__ bf16x8 pack8f(float4 f0, float4 f1){
  bf16x8 r;
  r[0]=(short)f2bf(f0.x); r[1]=(short)f2bf(f0.y); r[2]=(short)f2bf(f0.z); r[3]=(short)f2bf(f0.w);
  r[4]=(short)f2bf(f1.x); r[5]=(short)f2bf(f1.y); r[6]=(short)f2bf(f1.z); r[7]=(short)f2bf(f1.w);
  return r;
}
// async global->LDS, 16B per lane; LDS dest = uniform base + lane*16
__device__ __forceinline__ void gll16(const void* g, void* l){
  __builtin_amdgcn_global_load_lds(
      (const __attribute__((address_space(1))) u32*)g,
      (__attribute__((address_space(3))) u32*)l, 16, 0, 0);
}

// ---------- K1: per-row stats, w_uni, w_bi, unimodal (float2-paired) ----------
__global__ __launch_bounds__(256) void k1_stats(
    const float* __restrict__ x, const float* __restrict__ attW,
    const float* __restrict__ attb, float* __restrict__ stats,
    u16* __restrict__ Fcat, float* __restrict__ tw)
{
  int wave = threadIdx.x >> 6, lane = threadIdx.x & 63;
  int r = blockIdx.x * 4 + wave;
  const float2* xr  = (const float2*)(x + (size_t)r * 3 * DD);
  const float2* aw2 = (const float2*)attW;
  float2 a[8], v[8], l[8];
  float dA=0.f,dV=0.f,dL=0.f, mA=-1e30f,mV=-1e30f,mL=-1e30f;
  #pragma unroll
  for(int i = 0; i < 8; i++){
    int k2 = lane + i*64;
    a[i] = xr[k2]; v[i] = xr[512+k2]; l[i] = xr[1024+k2];
    float2 w = aw2[k2];
    dA = fmaf(a[i].x, w.x, fmaf(a[i].y, w.y, dA));
    dV = fmaf(v[i].x, w.x, fmaf(v[i].y, w.y, dV));
    dL = fmaf(l[i].x, w.x, fmaf(l[i].y, w.y, dL));
    mA = fmaxf(mA, fmaxf(a[i].x, a[i].y));
    mV = fmaxf(mV, fmaxf(v[i].x, v[i].y));
    mL = fmaxf(mL, fmaxf(l[i].x, l[i].y));
  }
  dA = wredsum(dA); dV = wredsum(dV); dL = wredsum(dL);
  mA = wredmax(mA); mV = wredmax(mV); mL = wredmax(mL);

  float Sa=0.f,Sv=0.f,Sl=0.f,Eav=0.f,Eal=0.f,Evl=0.f;
  #pragma unroll
  for(int i = 0; i < 8; i++){
    float eax = __expf(a[i].x-mA), eay = __expf(a[i].y-mA);
    float evx = __expf(v[i].x-mV), evy = __expf(v[i].y-mV);
    float elx = __expf(l[i].x-mL), ely = __expf(l[i].y-mL);
    Sa += eax+eay; Sv += evx+evy; Sl += elx+ely;
    Eav += eax*evx + eay*evy; Eal += eax*elx + eay*ely; Evl += evx*elx + evy*ely;
  }
  Sa = wredsum(Sa); Sv = wredsum(Sv); Sl = wredsum(Sl);
  Eav = wredsum(Eav); Eal = wredsum(Eal); Evl = wredsum(Evl);

  float ab = attb[0];
  float ta = fast_tanh(dA + ab), tv = fast_tanh(dV + ab), tl = fast_tanh(dL + ab);
  float mm = fmaxf(ta, fmaxf(tv, tl));
  float e0 = __expf(ta-mm), e1 = __expf(tv-mm), e2 = __expf(tl-mm);
  float ss = e0 + e1 + e2;
  float sa = e0/ss, sv = e1/ss, sl = e2/ss;
  float dav = Eav/(Sa*Sv), dal = Eal/(Sa*Sl), dvl = Evl/(Sv*Sl);
  float sav = (sa+sv)/(dav+0.5f);
  float sal = (sa+sl)/(dal+0.5f);
  float svl = (sv+sl)/(dvl+0.5f);
  float m2 = fmaxf(sav, fmaxf(sal, svl));
  float f0 = __expf(sav-m2), f1 = __expf(sal-m2), f2 = __expf(svl-m2);
  float s2 = f0 + f1 + f2;
  float wb0 = f0/s2, wb1 = f1/s2, wb2 = f2/s2;

  if(lane == 0){
    float* st = stats + (size_t)r*24;
    st[0]=sa; st[1]=sv; st[2]=sl;
    st[3]=wb0; st[4]=wb1; st[5]=wb2;
    st[6]=sav; st[7]=sal; st[8]=svl;
    st[9]=mA; st[10]=Sa; st[11]=mV; st[12]=Sv; st[13]=mL; st[14]=Sl;
    float* twr = tw + (size_t)r*12;
    twr[0]=sa; twr[1]=sv; twr[2]=sl; twr[3]=wb0; twr[4]=wb1; twr[5]=wb2;
  }
  u32* uniw = (u32*)(Fcat + (size_t)r*KF);
  #pragma unroll
  for(int i = 0; i < 8; i++){
    int k2 = lane + i*64;
    float ux = (sa*a[i].x + sv*v[i].x + sl*l[i].x) * (1.0f/3.0f);
    float uy = (sa*a[i].y + sv*v[i].y + sl*l[i].y) * (1.0f/3.0f);
    uniw[k2] = pack2bf(ux, uy);
  }
}

// ---------- precompute: Wb1 (128 x 1024 bf16): [n][k], n<64 -> U cols, else V ----------
__global__ __launch_bounds__(256) void kprew_b1(
    const float* __restrict__ W1, u16* __restrict__ Wb1)
{
  int idx = blockIdx.x * 256 + threadIdx.x;   // 0..131071
  int n = idx >> 10, k = idx & 1023;
  float v = (n < 64) ? W1[(size_t)k*64 + n] : W1[(size_t)(1024+k)*64 + (n-64)];
  Wb1[idx] = f2bf(v);
}

// ---------- precompute: W2T (1024 x 64 bf16): [c][k] = W2[k][c] ----------
__global__ __launch_bounds__(256) void kprew_w2t(
    const float* __restrict__ W2, u16* __restrict__ W2T)
{
  int idx = blockIdx.x * 256 + threadIdx.x;   // 0..65535
  int c = idx >> 6, k = idx & 63;
  W2T[idx] = f2bf(W2[(size_t)k*DD + c]);
}

// ---------- layer-1 MFMA GEMM: (3NB,1024) @ Wb1^T -> UV (3NB x 128 fp32) ----------
template<int FROM_X>
__global__ __launch_bounds__(256) void kg1v2(
    const float* __restrict__ xf, const u16* __restrict__ fc,
    const u16* __restrict__ Wb1, float* __restrict__ UV)
{
  __shared__ u16 Asm[2][64*64];   // 2 x 8KB
  int tid = threadIdx.x;
  int wv = tid >> 6, lane = tid & 63;
  int fr = lane & 15, kg = lane >> 4;
  int mb = blockIdx.x * 64;

  const u16* gsrc0 = nullptr; const u16* gsrc1 = nullptr;
  const float* xsrc0 = nullptr; const float* xsrc1 = nullptr;
  int rr_ = tid >> 3, pp_ = tid & 7;
  int sp_ = pp_ ^ (rr_ & 7);
  if(FROM_X){
    xsrc0 = xf + (size_t)(mb + rr_)*1024 + pp_*8;
    xsrc1 = xf + (size_t)(mb + rr_ + 32)*1024 + pp_*8;
  } else {
    int r8 = lane >> 3, p = lane & 7;
    int sp = p ^ (r8 & 7);
    int m0 = mb + (2*wv)*8 + r8;
    int m1 = mb + (2*wv+1)*8 + r8;
    int R0 = m0/3, R1 = m1/3;
    gsrc0 = fc + (size_t)R0*KF + (size_t)(1 + (m0 - 3*R0))*1024 + sp*8;
    gsrc1 = fc + (size_t)R1*KF + (size_t)(1 + (m1 - 3*R1))*1024 + sp*8;
  }

  f32x4 acc[4][2];
  #pragma unroll
  for(int rf = 0; rf < 4; rf++)
    #pragma unroll
    for(int nf = 0; nf < 2; nf++) acc[rf][nf] = (f32x4){0.f,0.f,0.f,0.f};

  if(FROM_X){
    float4 a0 = *(const float4*)xsrc0, a1 = *(const float4*)(xsrc0+4);
    float4 c0 = *(const float4*)xsrc1, c1 = *(const float4*)(xsrc1+4);
    *(bf16x8*)&Asm[0][rr_*64 + sp_*8]      = pack8f(a0,a1);
    *(bf16x8*)&Asm[0][(rr_+32)*64 + sp_*8] = pack8f(c0,c1);
  } else {
    gll16(gsrc0, &Asm[0][(2*wv)*512]);
    gll16(gsrc1, &Asm[0][(2*wv+1)*512]);
  }
  __syncthreads();

  int buf = 0;
  for(int ci = 0; ci < 16; ci++){
    int k0 = ci*64;
    float4 na0, na1, nc0, nc1;
    if(ci < 15){
      if(FROM_X){
        na0 = *(const float4*)(xsrc0 + k0 + 64); na1 = *(const float4*)(xsrc0 + k0 + 68);
        nc0 = *(const float4*)(xsrc1 + k0 + 64); nc1 = *(const float4*)(xsrc1 + k0 + 68);
      } else {
        gll16(gsrc0 + k0 + 64, &Asm[buf^1][(2*wv)*512]);
        gll16(gsrc1 + k0 + 64, &Asm[buf^1][(2*wv+1)*512]);
      }
    }
    #pragma unroll
    for(int ks = 0; ks < 2; ks++){
      bf16x8 a[4];
      #pragma unroll
      for(int rf = 0; rf < 4; rf++){
        int row = rf*16 + fr;
        int slot = (ks*4 + kg) ^ (fr & 7);
        a[rf] = *(const bf16x8*)&Asm[buf][row*64 + slot*8];
      }
      #pragma unroll
      for(int nf = 0; nf < 2; nf++){
        int col = wv*32 + nf*16 + fr;
        bf16x8 b = *(const bf16x8*)&Wb1[(size_t)col*1024 + k0 + ks*32 + kg*8];
        #pragma unroll
        for(int rf = 0; rf < 4; rf++)
          acc[rf][nf] = __builtin_amdgcn_mfma_f32_16x16x32_bf16(a[rf], b, acc[rf][nf], 0, 0, 0);
      }
    }
    if(FROM_X && ci < 15){
      *(bf16x8*)&Asm[buf^1][rr_*64 + sp_*8]      = pack8f(na0,na1);
      *(bf16x8*)&Asm[buf^1][(rr_+32)*64 + sp_*8] = pack8f(nc0,nc1);
    }
    __syncthreads();
    buf ^= 1;
  }

  #pragma unroll
  for(int rf = 0; rf < 4; rf++)
    #pragma unroll
    for(int nf = 0; nf < 2; nf++)
      #pragma unroll
      for(int q = 0; q < 4; q++)
        UV[(size_t)(mb + rf*16 + kg*4 + q)*128 + wv*32 + nf*16 + fr] = acc[rf][nf][q];
}

// ---------- layer-2 MFMA v3: one block = 16 rows x ALL 1024 cols ----------
// t-build + UV read ONCE per row; 4-pass cg loop over 256-col slabs;
// epilogue bounced through LDS for coalesced bf16x8 stores.
template<int P, int SUM>
__global__ __launch_bounds__(256) void kL2v3(
    const float* __restrict__ UVA, const float* __restrict__ UVB,
    const u16* __restrict__ W2T, const float* __restrict__ b1,
    const float* __restrict__ b2, const float* __restrict__ stats,
    u16* __restrict__ Fcat)
{
  const int NP = SUM ? 1 : P;          // output planes
  __shared__ u16 Tsm[P][16][64];       // swizzled t fragments
  __shared__ u16 Osm[SUM?1:P][16][264];// row-padded output bounce
  __shared__ float stw[16][8];
  int tid = threadIdx.x;
  int wv = tid >> 6, lane = tid & 63;
  int fr = lane & 15, kg = lane >> 4;
  int Rb = blockIdx.x * 16;

  // ---- phase 1: t = lrelu0.2(U+V+b1) -> Tsm (cooperative, coalesced) ----
  const int NG = P*16*8;
  for(int i = tid; i < NG; i += 256){
    int g = i & 7, r = (i >> 3) & 15, p = i >> 7;
    int R = Rb + r;
    int up, vp; const float* VBb;
    if(P == 3){
      up = (p == 2) ? 1 : 0;           // a1,a1,v1
      vp = (p == 0) ? 1 : 2;           // v1,l1,l1
      VBb = UVA;
    } else {
      up = (0x210200 >> (p*4)) & 15;   // a_v,a_v,v_l,a_v,a_l,v_l
      vp = (0x012112 >> (p*4)) & 15;   // v_l,a_l,a_l,l1,v1,a1
      VBb = (p < 3) ? UVA : UVB;
    }
    const float* Up = UVA + (size_t)(3*R + up)*128 + g*8;
    const float* Vp = VBb + (size_t)(3*R + vp)*128 + 64 + g*8;
    float4 u0 = *(const float4*)Up, u1 = *(const float4*)(Up+4);
    float4 v0 = *(const float4*)Vp, v1 = *(const float4*)(Vp+4);
    float4 bb0 = *(const float4*)(b1 + g*8), bb1 = *(const float4*)(b1 + g*8 + 4);
    float t[8] = {u0.x+v0.x+bb0.x, u0.y+v0.y+bb0.y, u0.z+v0.z+bb0.z, u0.w+v0.w+bb0.w,
                  u1.x+v1.x+bb1.x, u1.y+v1.y+bb1.y, u1.z+v1.z+bb1.z, u1.w+v1.w+bb1.w};
    bf16x8 o;
    #pragma unroll
    for(int j = 0; j < 8; j++){
      float tv = t[j] > 0.f ? t[j] : 0.2f*t[j];
      o[j] = (short)f2bf_tr(tv);
    }
    *(bf16x8*)&Tsm[p][r][(g ^ (r & 7))*8] = o;
  }
  if(tid < 16*P){
    int r = tid / P, p = tid - r*P;
    stw[r][p] = stats[(size_t)(Rb + r)*24 + (SUM ? 15 : 3) + p];
  }
  __syncthreads();

  // hoist A fragments (same for every cg)
  bf16x8 afr[2][P];
  #pragma unroll
  for(int ks = 0; ks < 2; ks++)
    #pragma unroll
    for(int p = 0; p < P; p++)
      afr[ks][p] = *(const bf16x8*)&Tsm[p][fr][(((ks<<2)+kg) ^ (fr & 7))*8];

  int orow = tid >> 4, oc16 = (tid & 15) * 16;   // store-out mapping

  for(int cg = 0; cg < 4; cg++){
    int cb = cg*256 + wv*64;
    f32x4 acc[P][4];
    #pragma unroll
    for(int p = 0; p < P; p++)
      #pragma unroll
      for(int cf = 0; cf < 4; cf++) acc[p][cf] = (f32x4){0.f,0.f,0.f,0.f};

    #pragma unroll
    for(int ks = 0; ks < 2; ks++)
      #pragma unroll
      for(int cf = 0; cf < 4; cf++){
        bf16x8 b = *(const bf16x8*)&W2T[(size_t)(cb + cf*16 + fr)*64 + ks*32 + kg*8];
        #pragma unroll
        for(int p = 0; p < P; p++)
          acc[p][cf] = __builtin_amdgcn_mfma_f32_16x16x32_bf16(afr[ks][p], b, acc[p][cf], 0, 0, 0);
      }

    if(cg > 0) __syncthreads();   // previous store-out readers done with Osm
    // epilogue -> Osm
    #pragma unroll
    for(int q = 0; q < 4; q++){
      int row = kg*4 + q;
      #pragma unroll
      for(int cf = 0; cf < 4; cf++){
        int cloc = wv*64 + cf*16 + fr;
        float b2c = b2[cg*256 + cloc];
        if(SUM){
          float s = 0.f;
          #pragma unroll
          for(int p = 0; p < P; p++){
            float g = stw[row][p] * fast_tanh(acc[p][cf][q] + b2c);
            s += g > 0.f ? g : 0.01f*g;
          }
          Osm[0][row][cloc] = f2bf(s * (1.0f/6.0f));
        } else {
          #pragma unroll
          for(int p = 0; p < P; p++){
            float g = stw[row][p] * fast_tanh(acc[p][cf][q] + b2c);
            float val = g > 0.f ? g : 0.01f*g;
            Osm[p][row][cloc] = f2bf(val);
          }
        }
      }
    }
    __syncthreads();
    // coalesced store-out: thread -> (row, 32B col chunk)
    #pragma unroll
    for(int p = 0; p < NP; p++){
      bf16x8 o0 = *(const bf16x8*)&Osm[p][orow][oc16];
      bf16x8 o1 = *(const bf16x8*)&Osm[p][orow][oc16 + 8];
      size_t off = (size_t)(Rb + orow)*KF + (SUM ? 4096 : (size_t)(1+p)*1024) + cg*256 + oc16;
      *(bf16x8*)&Fcat[off]     = o0;
      *(bf16x8*)&Fcat[off + 8] = o1;
    }
  }
}

// ---------- K3s: softmax stats of a_v/a_l/v_l + cross dots -> w_tri ----------
__global__ __launch_bounds__(256) void k3s_stats2(
    const u16* __restrict__ Fcat, const float* __restrict__ x,
    float* __restrict__ stats, float* __restrict__ tw)
{
  int wave = threadIdx.x >> 6, lane = threadIdx.x & 63;
  int r = blockIdx.x * 4 + wave;
  const u32* pv = (const u32*)(Fcat + (size_t)r*KF + 1024);
  const float2* xr = (const float2*)(x + (size_t)3*r*DD);
  float2 av[8], al[8], vl[8];
  float mav=-1e30f, mal=-1e30f, mvl=-1e30f;
  #pragma unroll
  for(int i = 0; i < 8; i++){
    int k2 = lane + i*64;
    u32 wa = pv[k2], wb = pv[512+k2], wc = pv[1024+k2];
    av[i] = make_float2(bf2f((u16)wa), bf2f((u16)(wa>>16)));
    al[i] = make_float2(bf2f((u16)wb), bf2f((u16)(wb>>16)));
    vl[i] = make_float2(bf2f((u16)wc), bf2f((u16)(wc>>16)));
    mav = fmaxf(mav, fmaxf(av[i].x, av[i].y));
    mal = fmaxf(mal, fmaxf(al[i].x, al[i].y));
    mvl = fmaxf(mvl, fmaxf(vl[i].x, vl[i].y));
  }
  mav = wredmax(mav); mal = wredmax(mal); mvl = wredmax(mvl);

  float* st = stats + (size_t)r*24;
  float sa=st[0], sv=st[1], sl=st[2];
  float sav=st[6], sal=st[7], svl=st[8];
  float mA=st[9], Sa=st[10], mV=st[11], Sv=st[12], mL=st[13], Sl=st[14];

  float Savv=0.f,Sall=0.f,Svll=0.f,E1=0.f,E2=0.f,E3=0.f,E4=0.f,E5=0.f,E6=0.f;
  #pragma unroll
  for(int i = 0; i < 8; i++){
    int k2 = lane + i*64;
    float2 a1 = xr[k2], v1 = xr[512+k2], l1 = xr[1024+k2];
    float eavx = __expf(av[i].x-mav), eavy = __expf(av[i].y-mav);
    float ealx = __expf(al[i].x-mal), ealy = __expf(al[i].y-mal);
    float evlx = __expf(vl[i].x-mvl), evly = __expf(vl[i].y-mvl);
    Savv += eavx+eavy; Sall += ealx+ealy; Svll += evlx+evly;
    float eax = __expf(a1.x-mA), eay = __expf(a1.y-mA);
    float evx = __expf(v1.x-mV), evy = __expf(v1.y-mV);
    float elx = __expf(l1.x-mL), ely = __expf(l1.y-mL);
    E1 += eavx*evlx + eavy*evly; E2 += eavx*ealx + eavy*ealy; E3 += ealx*evlx + ealy*evly;
    E4 += eavx*elx + eavy*ely;   E5 += ealx*evx + ealy*evy;   E6 += evlx*eax + evly*eay;
  }
  Savv = wredsum(Savv); Sall = wredsum(Sall); Svll = wredsum(Svll);
  E1 = wredsum(E1); E2 = wredsum(E2); E3 = wredsum(E3);
  E4 = wredsum(E4); E5 = wredsum(E5); E6 = wredsum(E6);

  float d1 = E1/(Savv*Svll), d2 = E2/(Savv*Sall), d3 = E3/(Sall*Svll);
  float d4 = E4/(Savv*Sl),   d5 = E5/(Sall*Sv),   d6 = E6/(Svll*Sa);
  float t0 = (sav+svl)/(d1+0.5f);
  float t1 = (sav+sal)/(d2+0.5f);
  float t2 = (sal+svl)/(d3+0.5f);
  float t3 = (sav+sl)/(d4+0.5f);
  float t4 = (sal+sv)/(d5+0.5f);
  float t5 = (sa+svl)/(d6+0.5f);
  float mx = fmaxf(fmaxf(fmaxf(t0,t1),fmaxf(t2,t3)),fmaxf(t4,t5));
  float g0=__expf(t0-mx),g1=__expf(t1-mx),g2=__expf(t2-mx);
  float g3=__expf(t3-mx),g4=__expf(t4-mx),g5=__expf(t5-mx);
  float gs = g0+g1+g2+g3+g4+g5;
  if(lane == 0){
    float wt[6] = {g0/gs,g1/gs,g2/gs,g3/gs,g4/gs,g5/gs};
    float* twr = tw + (size_t)r*12;
    #pragma unroll
    for(int p = 0; p < 6; p++){ st[15+p] = wt[p]; twr[6+p] = wt[p]; }
  }
}

// ---------- K6 precompute: WpT (64 x 5120 bf16), BN folded ----------
__global__ __launch_bounds__(256) void k6_prew(
    const float* __restrict__ gamma, const float* __restrict__ l1W,
    u16* __restrict__ WpT)
{
  int kk = blockIdx.x * 256 + threadIdx.x;   // 0..5119 (grid.x = 20)
  int j  = blockIdx.y;                        // 0..63
  const float gsc = 1.0f / sqrtf(1.0f + 1e-5f);
  int korig; float sc;
  if(kk < 1024){ korig = kk; sc = 1.f; }
  else if(kk < 4096){ korig = 1024 + ((kk - 1024) & 1023); sc = 1.0f/3.0f; }
  else { korig = 2048 + (kk - 4096); sc = 1.f; }
  float v = (j < 50) ? l1W[(size_t)korig*50 + j] * gamma[korig] * gsc * sc : 0.f;
  WpT[(size_t)j*KF + kk] = f2bf(v);
}

// ---------- K6 precompute: bp[j] = l1b[j] + beta @ l1W ----------
__global__ __launch_bounds__(256) void k6_preb(
    const float* __restrict__ beta, const float* __restrict__ l1W,
    const float* __restrict__ l1b, float* __restrict__ bp)
{
  __shared__ float red[4][64];
  int j = threadIdx.x & 63, seg = threadIdx.x >> 6;
  float s = 0.f;
  if(j < 50){
    for(int k = seg*768; k < seg*768 + 768; k++)
      s = fmaf(beta[k], l1W[(size_t)k*50 + j], s);
  }
  red[seg][j] = s;
  __syncthreads();
  if(seg == 0){
    float t = red[0][j] + red[1][j] + red[2][j] + red[3][j];
    bp[j] = (j < 50) ? (l1b[j] + t) : 0.f;
  }
}

// ---------- K6 v3: (NB x 5120)@(5120 x 64) + MLP tail ----------
__global__ __launch_bounds__(256) void k6v3(
    const u16* __restrict__ Fcat, const u16* __restrict__ WpT,
    const float* __restrict__ bp,
    const float* __restrict__ l2W, const float* __restrict__ l2b,
    const float* __restrict__ l3W, const float* __restrict__ l3b,
    float* __restrict__ y2out)
{
  __shared__ __align__(16) char smem[29760];
  u16*  Asm = (u16*)smem;                          // [2][2048] = 8 KB (stage)
  float* W2s = (float*)(smem + 8192);              // [50][64]  = 12.8 KB
  float* W3s = (float*)(smem + 8192 + 12800);      // [50][8]   = 1.6 KB
  float* Ys  = (float*)smem;                       // [32][56]  aliases Asm (7 KB)
  float* Ys2 = (float*)(smem + 8192 + 12800 + 1600); // [32][56] = 7 KB

  int tid = threadIdx.x;
  int wv = tid >> 6, lane = tid & 63;
  int fr = lane & 15, kg = lane >> 4;
  int rb = blockIdx.x * 32;

  for(int t = tid; t < 3200; t += 256){
    int c = t & 63;
    W2s[t] = (c < 50) ? l2W[(t >> 6)*50 + c] : 0.f;
  }
  for(int t = tid; t < 400; t += 256) W3s[t] = l3W[t];

  int r8 = lane >> 3, pp = lane & 7;
  int sp = pp ^ r8;
  const u16* gsrc = Fcat + (size_t)(rb + wv*8 + r8)*KF + sp*8;
  const u16* bptr = WpT  + (size_t)(fr)*KF + (size_t)wv*16*KF + kg*8;

  f32x4 acc[2];
  acc[0] = (f32x4){0.f,0.f,0.f,0.f};
  acc[1] = (f32x4){0.f,0.f,0.f,0.f};

  gll16(gsrc, &Asm[wv*512]);
  __syncthreads();

  int buf = 0;
  for(int ci = 0; ci < 80; ci++){
    int k0 = ci*64;
    if(ci < 79)
      gll16(gsrc + k0 + 64, &Asm[(buf^1)*2048 + wv*512]);
    #pragma unroll
    for(int ks = 0; ks < 2; ks++){
      bf16x8 b = *(const bf16x8*)(bptr + k0 + ks*32);
      #pragma unroll
      for(int rf = 0; rf < 2; rf++){
        int row = rf*16 + fr;
        int slot = (ks*4 + kg) ^ (fr & 7);
        bf16x8 a = *(const bf16x8*)&Asm[buf*2048 + row*64 + slot*8];
        acc[rf] = __builtin_amdgcn_mfma_f32_16x16x32_bf16(a, b, acc[rf], 0, 0, 0);
      }
    }
    __syncthreads();
    buf ^= 1;
  }

  {
    int col = wv*16 + fr;
    float bpc = bp[col];
    #pragma unroll
    for(int rf = 0; rf < 2; rf++)
      #pragma unroll
      for(int q = 0; q < 4; q++){
        int row = rf*16 + kg*4 + q;
        if(col < 50) Ys[row*56 + col] = fast_tanh(acc[rf][q] + bpc);
      }
  }
  __syncthreads();

  {
    int r = tid >> 3, cg = (tid & 7) * 7;
    float a2[7] = {0,0,0,0,0,0,0};
    for(int k = 0; k < 50; k++){
      float yv = Ys[r*56 + k];
      #pragma unroll
      for(int c = 0; c < 7; c++) a2[c] = fmaf(yv, W2s[k*64 + cg + c], a2[c]);
    }
    #pragma unroll
    for(int c = 0; c < 7; c++){
      int cc = cg + c;
      if(cc < 50) Ys2[r*56 + cc] = fast_tanh(a2[c] + l2b[cc]);
    }
  }
  __syncthreads();

  {
    int r = tid >> 3, c = tid & 7;
    float z = l3b[c];
    for(int k = 0; k < 50; k++) z = fmaf(Ys2[r*56 + k], W3s[k*8 + c], z);
    float m = z;
    m = fmaxf(m, __shfl_xor(m, 1));
    m = fmaxf(m, __shfl_xor(m, 2));
    m = fmaxf(m, __shfl_xor(m, 4));
    float e = __expf(z - m);
    float s = e;
    s += __shfl_xor(s, 1); s += __shfl_xor(s, 2); s += __shfl_xor(s, 4);
    y2out[(size_t)(rb + r)*8 + c] = e / s;
  }
}

// ---------- launch ----------
extern "C" void kernel_launch(void* const* d_in, const int* in_sizes, int n_in,
                              void* d_out, int out_size, void* d_ws, size_t ws_size,
                              hipStream_t stream)
{
  (void)in_sizes; (void)n_in; (void)out_size; (void)ws_size;
  const float* x    = (const float*)d_in[0];
  const float* attW = (const float*)d_in[1];
  const float* attb = (const float*)d_in[2];
  const float* gfW1 = (const float*)d_in[3];
  const float* gfb1 = (const float*)d_in[4];
  const float* gfW2 = (const float*)d_in[5];
  const float* gfb2 = (const float*)d_in[6];
  const float* bng  = (const float*)d_in[7];
  const float* bnb  = (const float*)d_in[8];
  const float* l1W  = (const float*)d_in[9];
  const float* l1b  = (const float*)d_in[10];
  const float* l2W  = (const float*)d_in[11];
  const float* l2b  = (const float*)d_in[12];
  const float* l3W  = (const float*)d_in[13];
  const float* l3b  = (const float*)d_in[14];

  float* out = (float*)d_out;
  float* tw  = out + (size_t)NB*8;

  // workspace layout
  float* ws    = (float*)d_ws;
  float* stats = ws;                               // NB*24 f32
  float* UV1   = stats + (size_t)NB*24;            // 3*NB*128 f32
  float* UV2   = UV1 + (size_t)3*NB*128;           // 3*NB*128 f32
  float* bp    = UV2 + (size_t)3*NB*128;           // 64 f32
  u16* WpT     = (u16*)(bp + 64);                  // 64*KF bf16
  u16* Wb1     = WpT + (size_t)64*KF;              // 128*1024 bf16
  u16* W2T     = Wb1 + (size_t)128*1024;           // 1024*64 bf16
  u16* Fcat    = W2T + (size_t)1024*64;            // NB*KF bf16

  k1_stats<<<dim3(NB/4), dim3(256), 0, stream>>>(x, attW, attb, stats, Fcat, tw);
  kprew_b1<<<dim3(512), dim3(256), 0, stream>>>(gfW1, Wb1);
  kprew_w2t<<<dim3(256), dim3(256), 0, stream>>>(gfW2, W2T);
  k6_prew<<<dim3(20, 64), dim3(256), 0, stream>>>(bng, l1W, WpT);
  k6_preb<<<dim3(1), dim3(256), 0, stream>>>(bnb, l1W, l1b, bp);

  kg1v2<1><<<dim3(3*NB/64), dim3(256), 0, stream>>>(x, (const u16*)nullptr, Wb1, UV1);
  kL2v3<3,0><<<dim3(NB/16), dim3(256), 0, stream>>>(UV1, UV1, W2T, gfb1, gfb2, stats, Fcat);
  k3s_stats2<<<dim3(NB/4), dim3(256), 0, stream>>>(Fcat, x, stats, tw);
  kg1v2<0><<<dim3(3*NB/64), dim3(256), 0, stream>>>((const float*)nullptr, Fcat, Wb1, UV2);
  kL2v3<6,1><<<dim3(NB/16), dim3(256), 0, stream>>>(UV2, UV1, W2T, gfb1, gfb2, stats, Fcat);
  k6v3<<<dim3(NB/32), dim3(256), 0, stream>>>(Fcat, WpT, bp, l2W, l2b, l3W, l3b, out);
}

// Round 8
// 406.661 us; speedup vs baseline: 1.1066x; 1.1066x over previous
//
#include <hip/hip_runtime.h>
#include <math.h>

#define NB 16384
#define DD 1024
#define KF 5120   // concat feature K: uni(1024) + a_v,a_l,v_l(3*1024) + tri(1024)

typedef unsigned short u16;
typedef unsigned int u32;
typedef __attribute__((ext_vector_type(8))) short bf16x8;
typedef __attribute__((ext_vector_type(4))) float f32x4;

// ---------- helpers ----------
__device__ __forceinline__ float bf2f(u16 u){
  return __uint_as_float(((unsigned)u) << 16);
}
__device__ __forceinline__ u16 f2bf(float f){
  unsigned u = __float_as_uint(f);
  return (u16)((u + 0x7fffu + ((u >> 16) & 1u)) >> 16);   // RNE
}
__device__ __forceinline__ u16 f2bf_tr(float f){           // cheap truncate (MFMA inputs only)
  return (u16)(__float_as_uint(f) >> 16);
}
__device__ __forceinline__ u32 pack2bf(float a, float b){
  return (u32)f2bf(a) | ((u32)f2bf(b) << 16);
}
__device__ __forceinline__ float fast_tanh(float x){
  float e = __expf(2.0f * x);
  return 1.0f - 2.0f * __builtin_amdgcn_rcpf(e + 1.0f);
}
__device__ __forceinline__ float wredsum(float x){
  #pragma unroll
  for(int o = 32; o >= 1; o >>= 1) x += __shfl_xor(x, o);
  return x;
}
__device__ __forceinline__ float wredmax(float x){
  #pragma unroll
  for(int o = 32; o >= 1; o >>= 1) x = fmaxf(x, __shfl_xor(x, o));
  return x;
}
// async global->LDS, 16B per lane; LDS dest = uniform base + lane*16
__device__ __forceinline__ void gll16(const void* g, void* l){
  __builtin_amdgcn_global_load_lds(
      (const __attribute__((address_space(1))) u32*)g,
      (__attribute__((address_space(3))) u32*)l, 16, 0, 0);
}

// ---------- K1: per-row stats, w_uni, w_bi, unimodal + xb (bf16 x copy) ----------
__global__ __launch_bounds__(256) void k1_stats(
    const float* __restrict__ x, const float* __restrict__ attW,
    const float* __restrict__ attb, float* __restrict__ stats,
    u16* __restrict__ Fcat, u16* __restrict__ xb, float* __restrict__ tw)
{
  int wave = threadIdx.x >> 6, lane = threadIdx.x & 63;
  int r = blockIdx.x * 4 + wave;
  const float2* xr  = (const float2*)(x + (size_t)r * 3 * DD);
  const float2* aw2 = (const float2*)attW;
  float2 a[8], v[8], l[8];
  float dA=0.f,dV=0.f,dL=0.f, mA=-1e30f,mV=-1e30f,mL=-1e30f;
  #pragma unroll
  for(int i = 0; i < 8; i++){
    int k2 = lane + i*64;
    a[i] = xr[k2]; v[i] = xr[512+k2]; l[i] = xr[1024+k2];
    float2 w = aw2[k2];
    dA = fmaf(a[i].x, w.x, fmaf(a[i].y, w.y, dA));
    dV = fmaf(v[i].x, w.x, fmaf(v[i].y, w.y, dV));
    dL = fmaf(l[i].x, w.x, fmaf(l[i].y, w.y, dL));
    mA = fmaxf(mA, fmaxf(a[i].x, a[i].y));
    mV = fmaxf(mV, fmaxf(v[i].x, v[i].y));
    mL = fmaxf(mL, fmaxf(l[i].x, l[i].y));
  }
  dA = wredsum(dA); dV = wredsum(dV); dL = wredsum(dL);
  mA = wredmax(mA); mV = wredmax(mV); mL = wredmax(mL);

  // write bf16 copy of x (consumed by kg1v3<0> and k3s)
  u32* xbw = (u32*)(xb + (size_t)3*r*DD);
  #pragma unroll
  for(int i = 0; i < 8; i++){
    int k2 = lane + i*64;
    xbw[k2]      = pack2bf(a[i].x, a[i].y);
    xbw[512+k2]  = pack2bf(v[i].x, v[i].y);
    xbw[1024+k2] = pack2bf(l[i].x, l[i].y);
  }

  float Sa=0.f,Sv=0.f,Sl=0.f,Eav=0.f,Eal=0.f,Evl=0.f;
  #pragma unroll
  for(int i = 0; i < 8; i++){
    float eax = __expf(a[i].x-mA), eay = __expf(a[i].y-mA);
    float evx = __expf(v[i].x-mV), evy = __expf(v[i].y-mV);
    float elx = __expf(l[i].x-mL), ely = __expf(l[i].y-mL);
    Sa += eax+eay; Sv += evx+evy; Sl += elx+ely;
    Eav += eax*evx + eay*evy; Eal += eax*elx + eay*ely; Evl += evx*elx + evy*ely;
  }
  Sa = wredsum(Sa); Sv = wredsum(Sv); Sl = wredsum(Sl);
  Eav = wredsum(Eav); Eal = wredsum(Eal); Evl = wredsum(Evl);

  float ab = attb[0];
  float ta = fast_tanh(dA + ab), tv = fast_tanh(dV + ab), tl = fast_tanh(dL + ab);
  float mm = fmaxf(ta, fmaxf(tv, tl));
  float e0 = __expf(ta-mm), e1 = __expf(tv-mm), e2 = __expf(tl-mm);
  float ss = e0 + e1 + e2;
  float sa = e0/ss, sv = e1/ss, sl = e2/ss;
  float dav = Eav/(Sa*Sv), dal = Eal/(Sa*Sl), dvl = Evl/(Sv*Sl);
  float sav = (sa+sv)/(dav+0.5f);
  float sal = (sa+sl)/(dal+0.5f);
  float svl = (sv+sl)/(dvl+0.5f);
  float m2 = fmaxf(sav, fmaxf(sal, svl));
  float f0 = __expf(sav-m2), f1 = __expf(sal-m2), f2 = __expf(svl-m2);
  float s2 = f0 + f1 + f2;
  float wb0 = f0/s2, wb1 = f1/s2, wb2 = f2/s2;

  if(lane == 0){
    float* st = stats + (size_t)r*24;
    st[0]=sa; st[1]=sv; st[2]=sl;
    st[3]=wb0; st[4]=wb1; st[5]=wb2;
    st[6]=sav; st[7]=sal; st[8]=svl;
    st[9]=mA; st[10]=Sa; st[11]=mV; st[12]=Sv; st[13]=mL; st[14]=Sl;
    float* twr = tw + (size_t)r*12;
    twr[0]=sa; twr[1]=sv; twr[2]=sl; twr[3]=wb0; twr[4]=wb1; twr[5]=wb2;
  }
  u32* uniw = (u32*)(Fcat + (size_t)r*KF);
  #pragma unroll
  for(int i = 0; i < 8; i++){
    int k2 = lane + i*64;
    float ux = (sa*a[i].x + sv*v[i].x + sl*l[i].x) * (1.0f/3.0f);
    float uy = (sa*a[i].y + sv*v[i].y + sl*l[i].y) * (1.0f/3.0f);
    uniw[k2] = pack2bf(ux, uy);
  }
}

// ---------- precompute: Wb1 (128 x 1024 bf16): [n][k], n<64 -> U cols, else V ----------
__global__ __launch_bounds__(256) void kprew_b1(
    const float* __restrict__ W1, u16* __restrict__ Wb1)
{
  int idx = blockIdx.x * 256 + threadIdx.x;   // 0..131071
  int n = idx >> 10, k = idx & 1023;
  float v = (n < 64) ? W1[(size_t)k*64 + n] : W1[(size_t)(1024+k)*64 + (n-64)];
  Wb1[idx] = f2bf(v);
}

// ---------- precompute: W2T (1024 x 64 bf16): [c][k] = W2[k][c] ----------
__global__ __launch_bounds__(256) void kprew_w2t(
    const float* __restrict__ W2, u16* __restrict__ W2T)
{
  int idx = blockIdx.x * 256 + threadIdx.x;   // 0..65535
  int c = idx >> 6, k = idx & 63;
  W2T[idx] = f2bf(W2[(size_t)k*DD + c]);
}

// ---------- layer-1 MFMA GEMM: (3NB,1024) @ Wb1^T -> UV (3NB x 128 fp32) ----------
// block: 256 thr / 4 waves; M-tile 64, N=128; waves split N (32 cols each).
// A (bf16 source) staged in LDS via gll16, double-buffered, XOR-swizzled.
template<int FCAT>
__global__ __launch_bounds__(256) void kg1v3(
    const u16* __restrict__ src, const u16* __restrict__ Wb1,
    float* __restrict__ UV)
{
  __shared__ u16 Asm[2][64*64];   // 2 x 8KB
  int tid = threadIdx.x;
  int wv = tid >> 6, lane = tid & 63;
  int fr = lane & 15, kg = lane >> 4;
  int mb = blockIdx.x * 64;

  int r8 = lane >> 3, p = lane & 7;
  int sp = p ^ r8;
  int m0 = mb + (2*wv)*8 + r8;
  int m1 = mb + (2*wv+1)*8 + r8;
  size_t b0, b1;
  if(FCAT){
    int R0 = m0/3, R1 = m1/3;
    b0 = (size_t)R0*KF + (size_t)(1 + (m0 - 3*R0))*1024;
    b1 = (size_t)R1*KF + (size_t)(1 + (m1 - 3*R1))*1024;
  } else {
    b0 = (size_t)m0*1024;
    b1 = (size_t)m1*1024;
  }
  const u16* gsrc0 = src + b0 + sp*8;
  const u16* gsrc1 = src + b1 + sp*8;

  f32x4 acc[4][2];
  #pragma unroll
  for(int rf = 0; rf < 4; rf++)
    #pragma unroll
    for(int nf = 0; nf < 2; nf++) acc[rf][nf] = (f32x4){0.f,0.f,0.f,0.f};

  gll16(gsrc0, &Asm[0][(2*wv)*512]);
  gll16(gsrc1, &Asm[0][(2*wv+1)*512]);
  __syncthreads();

  int buf = 0;
  for(int ci = 0; ci < 16; ci++){
    int k0 = ci*64;
    if(ci < 15){
      gll16(gsrc0 + k0 + 64, &Asm[buf^1][(2*wv)*512]);
      gll16(gsrc1 + k0 + 64, &Asm[buf^1][(2*wv+1)*512]);
    }
    #pragma unroll
    for(int ks = 0; ks < 2; ks++){
      bf16x8 a[4];
      #pragma unroll
      for(int rf = 0; rf < 4; rf++){
        int row = rf*16 + fr;
        int slot = (ks*4 + kg) ^ (row & 7);
        a[rf] = *(const bf16x8*)&Asm[buf][row*64 + slot*8];
      }
      #pragma unroll
      for(int nf = 0; nf < 2; nf++){
        int col = wv*32 + nf*16 + fr;
        bf16x8 b = *(const bf16x8*)&Wb1[(size_t)col*1024 + k0 + ks*32 + kg*8];
        #pragma unroll
        for(int rf = 0; rf < 4; rf++)
          acc[rf][nf] = __builtin_amdgcn_mfma_f32_16x16x32_bf16(a[rf], b, acc[rf][nf], 0, 0, 0);
      }
    }
    __syncthreads();
    buf ^= 1;
  }

  #pragma unroll
  for(int rf = 0; rf < 4; rf++)
    #pragma unroll
    for(int nf = 0; nf < 2; nf++)
      #pragma unroll
      for(int q = 0; q < 4; q++)
        UV[(size_t)(mb + rf*16 + kg*4 + q)*128 + wv*32 + nf*16 + fr] = acc[rf][nf][q];
}

// ---------- layer-2 MFMA v4: LDS t-build + LDS A-frags + coalesced Osm store ----------
// block: 16 rows x 256 cols, 4 waves (64 cols each), P pairs. grid (NB/16, 4).
template<int P, int SUM>
__global__ __launch_bounds__(256) void kL2v4(
    const float* __restrict__ UVA, const float* __restrict__ UVB,
    const u16* __restrict__ W2T, const float* __restrict__ b1,
    const float* __restrict__ b2, const float* __restrict__ stats,
    u16* __restrict__ Fcat)
{
  const int NP = SUM ? 1 : P;
  __shared__ u16 Tsm[P][16][64];       // swizzled t fragments
  __shared__ u16 Osm[NP][16][264];     // padded output bounce
  __shared__ float stw[16][8];
  int tid = threadIdx.x;
  int wv = tid >> 6, lane = tid & 63;
  int fr = lane & 15, kg = lane >> 4;
  int Rb = blockIdx.x * 16;
  int cb = blockIdx.y * 256 + wv * 64;

  // ---- phase 1: t = lrelu0.2(U+V+b1) -> Tsm (cooperative, coalesced) ----
  const int NG = P*16*8;
  for(int i = tid; i < NG; i += 256){
    int g = i & 7, r = (i >> 3) & 15, p = i >> 7;
    int R = Rb + r;
    int up, vp; const float* VBb;
    if(P == 3){
      up = (p == 2) ? 1 : 0;           // a1,a1,v1
      vp = (p == 0) ? 1 : 2;           // v1,l1,l1
      VBb = UVA;
    } else {
      up = (0x210200 >> (p*4)) & 15;   // a_v,a_v,v_l,a_v,a_l,v_l
      vp = (0x012112 >> (p*4)) & 15;   // v_l,a_l,a_l,l1,v1,a1
      VBb = (p < 3) ? UVA : UVB;
    }
    const float* Up = UVA + (size_t)(3*R + up)*128 + g*8;
    const float* Vp = VBb + (size_t)(3*R + vp)*128 + 64 + g*8;
    float4 u0 = *(const float4*)Up, u1 = *(const float4*)(Up+4);
    float4 v0 = *(const float4*)Vp, v1 = *(const float4*)(Vp+4);
    float4 bb0 = *(const float4*)(b1 + g*8), bb1 = *(const float4*)(b1 + g*8 + 4);
    float t[8] = {u0.x+v0.x+bb0.x, u0.y+v0.y+bb0.y, u0.z+v0.z+bb0.z, u0.w+v0.w+bb0.w,
                  u1.x+v1.x+bb1.x, u1.y+v1.y+bb1.y, u1.z+v1.z+bb1.z, u1.w+v1.w+bb1.w};
    bf16x8 o;
    #pragma unroll
    for(int j = 0; j < 8; j++){
      float tv = t[j] > 0.f ? t[j] : 0.2f*t[j];
      o[j] = (short)f2bf_tr(tv);
    }
    *(bf16x8*)&Tsm[p][r][(g ^ (r & 7))*8] = o;
  }
  if(tid < 16*P){
    int r = tid / P, p = tid - r*P;
    stw[r][p] = stats[(size_t)(Rb + r)*24 + (SUM ? 15 : 3) + p];
  }
  __syncthreads();

  // ---- phase 2: MFMA (A from LDS, B from global/L1) ----
  f32x4 acc[P][4];
  #pragma unroll
  for(int p = 0; p < P; p++)
    #pragma unroll
    for(int cf = 0; cf < 4; cf++) acc[p][cf] = (f32x4){0.f,0.f,0.f,0.f};

  #pragma unroll
  for(int ks = 0; ks < 2; ks++){
    bf16x8 a[P];
    #pragma unroll
    for(int p = 0; p < P; p++)
      a[p] = *(const bf16x8*)&Tsm[p][fr][(((ks<<2)+kg) ^ (fr & 7))*8];
    #pragma unroll
    for(int cf = 0; cf < 4; cf++){
      bf16x8 b = *(const bf16x8*)&W2T[(size_t)(cb + cf*16 + fr)*64 + ks*32 + kg*8];
      #pragma unroll
      for(int p = 0; p < P; p++)
        acc[p][cf] = __builtin_amdgcn_mfma_f32_16x16x32_bf16(a[p], b, acc[p][cf], 0, 0, 0);
    }
  }

  // ---- phase 3: epilogue -> Osm (tanh/weights/lrelu), then coalesced store ----
  #pragma unroll
  for(int q = 0; q < 4; q++){
    int row = kg*4 + q;
    #pragma unroll
    for(int cf = 0; cf < 4; cf++){
      int cloc = wv*64 + cf*16 + fr;
      float b2c = b2[blockIdx.y*256 + cloc];
      if(SUM){
        float s = 0.f;
        #pragma unroll
        for(int p = 0; p < P; p++){
          float g = stw[row][p] * fast_tanh(acc[p][cf][q] + b2c);
          s += g > 0.f ? g : 0.01f*g;
        }
        Osm[0][row][cloc] = f2bf(s * (1.0f/6.0f));
      } else {
        #pragma unroll
        for(int p = 0; p < P; p++){
          float g = stw[row][p] * fast_tanh(acc[p][cf][q] + b2c);
          float val = g > 0.f ? g : 0.01f*g;
          Osm[p][row][cloc] = f2bf(val);
        }
      }
    }
  }
  __syncthreads();
  {
    int orow = tid >> 4, oc16 = (tid & 15) * 16;
    #pragma unroll
    for(int p = 0; p < NP; p++){
      bf16x8 o0 = *(const bf16x8*)&Osm[p][orow][oc16];
      bf16x8 o1 = *(const bf16x8*)&Osm[p][orow][oc16 + 8];
      size_t off = (size_t)(Rb + orow)*KF + (SUM ? 4096 : (size_t)(1+p)*1024)
                 + blockIdx.y*256 + oc16;
      *(bf16x8*)&Fcat[off]     = o0;
      *(bf16x8*)&Fcat[off + 8] = o1;
    }
  }
}

// ---------- K3s: softmax stats of a_v/a_l/v_l + cross dots -> w_tri (bf16 x) ----------
__global__ __launch_bounds__(256) void k3s_stats2(
    const u16* __restrict__ Fcat, const u16* __restrict__ xb,
    float* __restrict__ stats, float* __restrict__ tw)
{
  int wave = threadIdx.x >> 6, lane = threadIdx.x & 63;
  int r = blockIdx.x * 4 + wave;
  const u32* pv = (const u32*)(Fcat + (size_t)r*KF + 1024);
  const u32* xv = (const u32*)(xb + (size_t)3*r*DD);
  float2 av[8], al[8], vl[8];
  float mav=-1e30f, mal=-1e30f, mvl=-1e30f;
  #pragma unroll
  for(int i = 0; i < 8; i++){
    int k2 = lane + i*64;
    u32 wa = pv[k2], wb = pv[512+k2], wc = pv[1024+k2];
    av[i] = make_float2(bf2f((u16)wa), bf2f((u16)(wa>>16)));
    al[i] = make_float2(bf2f((u16)wb), bf2f((u16)(wb>>16)));
    vl[i] = make_float2(bf2f((u16)wc), bf2f((u16)(wc>>16)));
    mav = fmaxf(mav, fmaxf(av[i].x, av[i].y));
    mal = fmaxf(mal, fmaxf(al[i].x, al[i].y));
    mvl = fmaxf(mvl, fmaxf(vl[i].x, vl[i].y));
  }
  mav = wredmax(mav); mal = wredmax(mal); mvl = wredmax(mvl);

  float* st = stats + (size_t)r*24;
  float sa=st[0], sv=st[1], sl=st[2];
  float sav=st[6], sal=st[7], svl=st[8];
  float mA=st[9], Sa=st[10], mV=st[11], Sv=st[12], mL=st[13], Sl=st[14];

  float Savv=0.f,Sall=0.f,Svll=0.f,E1=0.f,E2=0.f,E3=0.f,E4=0.f,E5=0.f,E6=0.f;
  #pragma unroll
  for(int i = 0; i < 8; i++){
    int k2 = lane + i*64;
    u32 xa = xv[k2], xvv = xv[512+k2], xl = xv[1024+k2];
    float a1x = bf2f((u16)xa),  a1y = bf2f((u16)(xa>>16));
    float v1x = bf2f((u16)xvv), v1y = bf2f((u16)(xvv>>16));
    float l1x = bf2f((u16)xl),  l1y = bf2f((u16)(xl>>16));
    float eavx = __expf(av[i].x-mav), eavy = __expf(av[i].y-mav);
    float ealx = __expf(al[i].x-mal), ealy = __expf(al[i].y-mal);
    float evlx = __expf(vl[i].x-mvl), evly = __expf(vl[i].y-mvl);
    Savv += eavx+eavy; Sall += ealx+ealy; Svll += evlx+evly;
    float eax = __expf(a1x-mA), eay = __expf(a1y-mA);
    float evx = __expf(v1x-mV), evy = __expf(v1y-mV);
    float elx = __expf(l1x-mL), ely = __expf(l1y-mL);
    E1 += eavx*evlx + eavy*evly; E2 += eavx*ealx + eavy*ealy; E3 += ealx*evlx + ealy*evly;
    E4 += eavx*elx + eavy*ely;   E5 += ealx*evx + ealy*evy;   E6 += evlx*eax + evly*eay;
  }
  Savv = wredsum(Savv); Sall = wredsum(Sall); Svll = wredsum(Svll);
  E1 = wredsum(E1); E2 = wredsum(E2); E3 = wredsum(E3);
  E4 = wredsum(E4); E5 = wredsum(E5); E6 = wredsum(E6);

  float d1 = E1/(Savv*Svll), d2 = E2/(Savv*Sall), d3 = E3/(Sall*Svll);
  float d4 = E4/(Savv*Sl),   d5 = E5/(Sall*Sv),   d6 = E6/(Svll*Sa);
  float t0 = (sav+svl)/(d1+0.5f);
  float t1 = (sav+sal)/(d2+0.5f);
  float t2 = (sal+svl)/(d3+0.5f);
  float t3 = (sav+sl)/(d4+0.5f);
  float t4 = (sal+sv)/(d5+0.5f);
  float t5 = (sa+svl)/(d6+0.5f);
  float mx = fmaxf(fmaxf(fmaxf(t0,t1),fmaxf(t2,t3)),fmaxf(t4,t5));
  float g0=__expf(t0-mx),g1=__expf(t1-mx),g2=__expf(t2-mx);
  float g3=__expf(t3-mx),g4=__expf(t4-mx),g5=__expf(t5-mx);
  float gs = g0+g1+g2+g3+g4+g5;
  if(lane == 0){
    float wt[6] = {g0/gs,g1/gs,g2/gs,g3/gs,g4/gs,g5/gs};
    float* twr = tw + (size_t)r*12;
    #pragma unroll
    for(int p = 0; p < 6; p++){ st[15+p] = wt[p]; twr[6+p] = wt[p]; }
  }
}

// ---------- K6 precompute: WpT (64 x 5120 bf16), BN folded ----------
__global__ __launch_bounds__(256) void k6_prew(
    const float* __restrict__ gamma, const float* __restrict__ l1W,
    u16* __restrict__ WpT)
{
  int kk = blockIdx.x * 256 + threadIdx.x;   // 0..5119 (grid.x = 20)
  int j  = blockIdx.y;                        // 0..63
  const float gsc = 1.0f / sqrtf(1.0f + 1e-5f);
  int korig; float sc;
  if(kk < 1024){ korig = kk; sc = 1.f; }
  else if(kk < 4096){ korig = 1024 + ((kk - 1024) & 1023); sc = 1.0f/3.0f; }
  else { korig = 2048 + (kk - 4096); sc = 1.f; }
  float v = (j < 50) ? l1W[(size_t)korig*50 + j] * gamma[korig] * gsc * sc : 0.f;
  WpT[(size_t)j*KF + kk] = f2bf(v);
}

// ---------- K6 precompute: bp[j] = l1b[j] + beta @ l1W ----------
__global__ __launch_bounds__(256) void k6_preb(
    const float* __restrict__ beta, const float* __restrict__ l1W,
    const float* __restrict__ l1b, float* __restrict__ bp)
{
  __shared__ float red[4][64];
  int j = threadIdx.x & 63, seg = threadIdx.x >> 6;
  float s = 0.f;
  if(j < 50){
    for(int k = seg*768; k < seg*768 + 768; k++)
      s = fmaf(beta[k], l1W[(size_t)k*50 + j], s);
  }
  red[seg][j] = s;
  __syncthreads();
  if(seg == 0){
    float t = red[0][j] + red[1][j] + red[2][j] + red[3][j];
    bp[j] = (j < 50) ? (l1b[j] + t) : 0.f;
  }
}

// ---------- K6 v4: (NB x 5120)@(5120 x 64) + MLP tail; 128-wide K chunks ----------
// M-tile 32, 256 thr / 4 waves; wave = 16-col fragment, full K.
// A LDS-staged (2 gll16/wave/chunk, XOR-swizzle), double-buffered.
__global__ __launch_bounds__(256) void k6v4(
    const u16* __restrict__ Fcat, const u16* __restrict__ WpT,
    const float* __restrict__ bp,
    const float* __restrict__ l2W, const float* __restrict__ l2b,
    const float* __restrict__ l3W, const float* __restrict__ l3b,
    float* __restrict__ y2out)
{
  __shared__ __align__(16) char smem[37952];
  u16*  Asm = (u16*)smem;                            // [2][4096] = 16 KB (stage)
  float* W2s = (float*)(smem + 16384);               // [50][64]  = 12.8 KB
  float* W3s = (float*)(smem + 16384 + 12800);       // [50][8]   = 1.6 KB
  float* Ys  = (float*)smem;                         // [32][56]  aliases Asm
  float* Ys2 = (float*)(smem + 16384 + 12800 + 1600);// [32][56]  = 7 KB

  int tid = threadIdx.x;
  int wv = tid >> 6, lane = tid & 63;
  int fr = lane & 15, kg = lane >> 4;
  int rb = blockIdx.x * 32;

  for(int t = tid; t < 3200; t += 256){
    int c = t & 63;
    W2s[t] = (c < 50) ? l2W[(t >> 6)*50 + c] : 0.f;
  }
  for(int t = tid; t < 400; t += 256) W3s[t] = l3W[t];

  // staging: wave wv covers rows wv*8..wv*8+7; chunk = 32 rows x 128 k (8 KB)
  // LDS layout: [wave slab 1024 u16][k-half 512][r8 64][k-part 8], sp = p ^ r8
  int r8 = lane >> 3, pp = lane & 7;
  int sp = pp ^ r8;
  const u16* gsrc = Fcat + (size_t)(rb + wv*8 + r8)*KF + sp*8;   // + kh*64 + k0
  const u16* bptr = WpT  + (size_t)(wv*16 + fr)*KF + kg*8;

  f32x4 acc[2];
  acc[0] = (f32x4){0.f,0.f,0.f,0.f};
  acc[1] = (f32x4){0.f,0.f,0.f,0.f};

  gll16(gsrc,      &Asm[wv*1024]);
  gll16(gsrc + 64, &Asm[wv*1024 + 512]);
  __syncthreads();

  int buf = 0;
  for(int ci = 0; ci < 40; ci++){
    int k0 = ci*128;
    if(ci < 39){
      gll16(gsrc + k0 + 128, &Asm[(buf^1)*4096 + wv*1024]);
      gll16(gsrc + k0 + 192, &Asm[(buf^1)*4096 + wv*1024 + 512]);
    }
    #pragma unroll
    for(int kh = 0; kh < 2; kh++){
      #pragma unroll
      for(int ks = 0; ks < 2; ks++){
        bf16x8 b = *(const bf16x8*)(bptr + k0 + kh*64 + ks*32);
        #pragma unroll
        for(int rf = 0; rf < 2; rf++){
          int row = rf*16 + fr;
          int slot = ((ks<<2) + kg) ^ (row & 7);
          bf16x8 a = *(const bf16x8*)&Asm[buf*4096 + (row>>3)*1024 + kh*512
                                          + (row & 7)*64 + slot*8];
          acc[rf] = __builtin_amdgcn_mfma_f32_16x16x32_bf16(a, b, acc[rf], 0, 0, 0);
        }
      }
    }
    __syncthreads();
    buf ^= 1;
  }

  // epilogue: Ys[row][col] = tanh(acc + bp)   (aliases Asm -- after final barrier)
  {
    int col = wv*16 + fr;
    float bpc = bp[col];
    #pragma unroll
    for(int rf = 0; rf < 2; rf++)
      #pragma unroll
      for(int q = 0; q < 4; q++){
        int row = rf*16 + kg*4 + q;
        if(col < 50) Ys[row*56 + col] = fast_tanh(acc[rf][q] + bpc);
      }
  }
  __syncthreads();

  // stage 2: Ys(32x50) @ W2 -> tanh -> Ys2
  {
    int r = tid >> 3, cg = (tid & 7) * 7;
    float a2[7] = {0,0,0,0,0,0,0};
    for(int k = 0; k < 50; k++){
      float yv = Ys[r*56 + k];
      #pragma unroll
      for(int c = 0; c < 7; c++) a2[c] = fmaf(yv, W2s[k*64 + cg + c], a2[c]);
    }
    #pragma unroll
    for(int c = 0; c < 7; c++){
      int cc = cg + c;
      if(cc < 50) Ys2[r*56 + cc] = fast_tanh(a2[c] + l2b[cc]);
    }
  }
  __syncthreads();

  // stage 3: Ys2(32x50) @ W3 + b3, softmax over 8
  {
    int r = tid >> 3, c = tid & 7;
    float z = l3b[c];
    for(int k = 0; k < 50; k++) z = fmaf(Ys2[r*56 + k], W3s[k*8 + c], z);
    float m = z;
    m = fmaxf(m, __shfl_xor(m, 1));
    m = fmaxf(m, __shfl_xor(m, 2));
    m = fmaxf(m, __shfl_xor(m, 4));
    float e = __expf(z - m);
    float s = e;
    s += __shfl_xor(s, 1); s += __shfl_xor(s, 2); s += __shfl_xor(s, 4);
    y2out[(size_t)(rb + r)*8 + c] = e / s;
  }
}

// ---------- launch ----------
extern "C" void kernel_launch(void* const* d_in, const int* in_sizes, int n_in,
                              void* d_out, int out_size, void* d_ws, size_t ws_size,
                              hipStream_t stream)
{
  (void)in_sizes; (void)n_in; (void)out_size; (void)ws_size;
  const float* x    = (const float*)d_in[0];
  const float* attW = (const float*)d_in[1];
  const float* attb = (const float*)d_in[2];
  const float* gfW1 = (const float*)d_in[3];
  const float* gfb1 = (const float*)d_in[4];
  const float* gfW2 = (const float*)d_in[5];
  const float* gfb2 = (const float*)d_in[6];
  const float* bng  = (const float*)d_in[7];
  const float* bnb  = (const float*)d_in[8];
  const float* l1W  = (const float*)d_in[9];
  const float* l1b  = (const float*)d_in[10];
  const float* l2W  = (const float*)d_in[11];
  const float* l2b  = (const float*)d_in[12];
  const float* l3W  = (const float*)d_in[13];
  const float* l3b  = (const float*)d_in[14];

  float* out = (float*)d_out;
  float* tw  = out + (size_t)NB*8;

  // workspace layout (~321 MB)
  float* ws    = (float*)d_ws;
  float* stats = ws;                               // NB*24 f32
  float* UV1   = stats + (size_t)NB*24;            // 3*NB*128 f32
  float* UV2   = UV1 + (size_t)3*NB*128;           // 3*NB*128 f32
  float* bp    = UV2 + (size_t)3*NB*128;           // 64 f32
  u16* WpT     = (u16*)(bp + 64);                  // 64*KF bf16
  u16* Wb1     = WpT + (size_t)64*KF;              // 128*1024 bf16
  u16* W2T     = Wb1 + (size_t)128*1024;           // 1024*64 bf16
  u16* Fcat    = W2T + (size_t)1024*64;            // NB*KF bf16
  u16* xb      = Fcat + (size_t)NB*KF;             // 3*NB*1024 bf16

  k1_stats<<<dim3(NB/4), dim3(256), 0, stream>>>(x, attW, attb, stats, Fcat, xb, tw);
  kprew_b1<<<dim3(512), dim3(256), 0, stream>>>(gfW1, Wb1);
  kprew_w2t<<<dim3(256), dim3(256), 0, stream>>>(gfW2, W2T);
  k6_prew<<<dim3(20, 64), dim3(256), 0, stream>>>(bng, l1W, WpT);
  k6_preb<<<dim3(1), dim3(256), 0, stream>>>(bnb, l1W, l1b, bp);

  kg1v3<0><<<dim3(3*NB/64), dim3(256), 0, stream>>>(xb, Wb1, UV1);
  kL2v4<3,0><<<dim3(NB/16, 4), dim3(256), 0, stream>>>(UV1, UV1, W2T, gfb1, gfb2, stats, Fcat);
  k3s_stats2<<<dim3(NB/4), dim3(256), 0, stream>>>(Fcat, xb, stats, tw);
  kg1v3<1><<<dim3(3*NB/64), dim3(256), 0, stream>>>(Fcat, Wb1, UV2);
  kL2v4<6,1><<<dim3(NB/16, 4), dim3(256), 0, stream>>>(UV2, UV1, W2T, gfb1, gfb2, stats, Fcat);
  k6v4<<<dim3(NB/32), dim3(256), 0, stream>>>(Fcat, WpT, bp, l2W, l2b, l3W, l3b, out);
}

// Round 9
// 392.580 us; speedup vs baseline: 1.1463x; 1.0359x over previous
//
#include <hip/hip_runtime.h>
#include <math.h>

#define NB 16384
#define DD 1024
#define KF 5120   // concat feature K: uni(1024) + a_v,a_l,v_l(3*1024) + tri(1024)

typedef unsigned short u16;
typedef unsigned int u32;
typedef __attribute__((ext_vector_type(8))) short bf16x8;
typedef __attribute__((ext_vector_type(4))) float f32x4;

// ---------- helpers ----------
__device__ __forceinline__ float bf2f(u16 u){
  return __uint_as_float(((unsigned)u) << 16);
}
__device__ __forceinline__ u16 f2bf(float f){
  unsigned u = __float_as_uint(f);
  return (u16)((u + 0x7fffu + ((u >> 16) & 1u)) >> 16);   // RNE
}
__device__ __forceinline__ u16 f2bf_tr(float f){           // cheap truncate (MFMA inputs only)
  return (u16)(__float_as_uint(f) >> 16);
}
__device__ __forceinline__ u32 pack2bf(float a, float b){
  return (u32)f2bf(a) | ((u32)f2bf(b) << 16);
}
__device__ __forceinline__ float fast_tanh(float x){
  float e = __expf(2.0f * x);
  return 1.0f - 2.0f * __builtin_amdgcn_rcpf(e + 1.0f);
}
__device__ __forceinline__ float wredsum(float x){
  #pragma unroll
  for(int o = 32; o >= 1; o >>= 1) x += __shfl_xor(x, o);
  return x;
}
__device__ __forceinline__ float wredmax(float x){
  #pragma unroll
  for(int o = 32; o >= 1; o >>= 1) x = fmaxf(x, __shfl_xor(x, o));
  return x;
}
// async global->LDS, 16B per lane; LDS dest = uniform base + lane*16
__device__ __forceinline__ void gll16(const void* g, void* l){
  __builtin_amdgcn_global_load_lds(
      (const __attribute__((address_space(1))) u32*)g,
      (__attribute__((address_space(3))) u32*)l, 16, 0, 0);
}

// ---------- kpre: all weight precompute + y1g zero (merged) ----------
__global__ __launch_bounds__(256) void kpre(
    const float* __restrict__ W1, const float* __restrict__ W2,
    const float* __restrict__ gamma, const float* __restrict__ beta,
    const float* __restrict__ l1W, const float* __restrict__ l1b,
    u16* __restrict__ Wb1, u16* __restrict__ W2T, u16* __restrict__ WpT,
    float* __restrict__ bp, float* __restrict__ y1g)
{
  __shared__ float red[4][64];
  int b = blockIdx.x, tid = threadIdx.x;
  if(b < 512){                                  // Wb1 (128 x 1024): [n][k]
    int idx = b*256 + tid;
    int n = idx >> 10, k = idx & 1023;
    float v = (n < 64) ? W1[(size_t)k*64 + n] : W1[(size_t)(1024+k)*64 + (n-64)];
    Wb1[idx] = f2bf(v);
  } else if(b < 768){                           // W2T (1024 x 64): [c][k]
    int idx = (b-512)*256 + tid;
    int c = idx >> 6, k = idx & 63;
    W2T[idx] = f2bf(W2[(size_t)k*DD + c]);
  } else if(b < 768 + 1280){                    // WpT (64 x 5120), BN folded
    int idx = (b-768)*256 + tid;
    int j = idx / KF, kk = idx - j*KF;
    const float gsc = 1.0f / sqrtf(1.0f + 1e-5f);
    int korig; float sc;
    if(kk < 1024){ korig = kk; sc = 1.f; }
    else if(kk < 4096){ korig = 1024 + ((kk - 1024) & 1023); sc = 1.0f/3.0f; }
    else { korig = 2048 + (kk - 4096); sc = 1.f; }
    float v = (j < 50) ? l1W[(size_t)korig*50 + j] * gamma[korig] * gsc * sc : 0.f;
    WpT[(size_t)j*KF + kk] = f2bf(v);
  } else if(b < 768 + 1280 + 1024){             // zero y1g (NB*64 f32)
    int idx = (b - 2048)*256 + tid;
    ((float4*)y1g)[idx] = make_float4(0.f,0.f,0.f,0.f);
  } else {                                      // bp[j] = l1b[j] + beta @ l1W
    int j = tid & 63, seg = tid >> 6;
    float s = 0.f;
    if(j < 50){
      for(int k = seg*768; k < seg*768 + 768; k++)
        s = fmaf(beta[k], l1W[(size_t)k*50 + j], s);
    }
    red[seg][j] = s;
    __syncthreads();
    if(seg == 0){
      float t = red[0][j] + red[1][j] + red[2][j] + red[3][j];
      bp[j] = (j < 50) ? (l1b[j] + t) : 0.f;
    }
  }
}

// ---------- K1: per-row stats, w_uni, w_bi, uniB + xb ----------
__global__ __launch_bounds__(256) void k1_stats(
    const float* __restrict__ x, const float* __restrict__ attW,
    const float* __restrict__ attb, float* __restrict__ stats,
    u16* __restrict__ uniB, u16* __restrict__ xb, float* __restrict__ tw)
{
  int wave = threadIdx.x >> 6, lane = threadIdx.x & 63;
  int r = blockIdx.x * 4 + wave;
  const float2* xr  = (const float2*)(x + (size_t)r * 3 * DD);
  const float2* aw2 = (const float2*)attW;
  float2 a[8], v[8], l[8];
  float dA=0.f,dV=0.f,dL=0.f, mA=-1e30f,mV=-1e30f,mL=-1e30f;
  #pragma unroll
  for(int i = 0; i < 8; i++){
    int k2 = lane + i*64;
    a[i] = xr[k2]; v[i] = xr[512+k2]; l[i] = xr[1024+k2];
    float2 w = aw2[k2];
    dA = fmaf(a[i].x, w.x, fmaf(a[i].y, w.y, dA));
    dV = fmaf(v[i].x, w.x, fmaf(v[i].y, w.y, dV));
    dL = fmaf(l[i].x, w.x, fmaf(l[i].y, w.y, dL));
    mA = fmaxf(mA, fmaxf(a[i].x, a[i].y));
    mV = fmaxf(mV, fmaxf(v[i].x, v[i].y));
    mL = fmaxf(mL, fmaxf(l[i].x, l[i].y));
  }
  dA = wredsum(dA); dV = wredsum(dV); dL = wredsum(dL);
  mA = wredmax(mA); mV = wredmax(mV); mL = wredmax(mL);

  u32* xbw = (u32*)(xb + (size_t)3*r*DD);
  #pragma unroll
  for(int i = 0; i < 8; i++){
    int k2 = lane + i*64;
    xbw[k2]      = pack2bf(a[i].x, a[i].y);
    xbw[512+k2]  = pack2bf(v[i].x, v[i].y);
    xbw[1024+k2] = pack2bf(l[i].x, l[i].y);
  }

  float Sa=0.f,Sv=0.f,Sl=0.f,Eav=0.f,Eal=0.f,Evl=0.f;
  #pragma unroll
  for(int i = 0; i < 8; i++){
    float eax = __expf(a[i].x-mA), eay = __expf(a[i].y-mA);
    float evx = __expf(v[i].x-mV), evy = __expf(v[i].y-mV);
    float elx = __expf(l[i].x-mL), ely = __expf(l[i].y-mL);
    Sa += eax+eay; Sv += evx+evy; Sl += elx+ely;
    Eav += eax*evx + eay*evy; Eal += eax*elx + eay*ely; Evl += evx*elx + evy*ely;
  }
  Sa = wredsum(Sa); Sv = wredsum(Sv); Sl = wredsum(Sl);
  Eav = wredsum(Eav); Eal = wredsum(Eal); Evl = wredsum(Evl);

  float ab = attb[0];
  float ta = fast_tanh(dA + ab), tv = fast_tanh(dV + ab), tl = fast_tanh(dL + ab);
  float mm = fmaxf(ta, fmaxf(tv, tl));
  float e0 = __expf(ta-mm), e1 = __expf(tv-mm), e2 = __expf(tl-mm);
  float ss = e0 + e1 + e2;
  float sa = e0/ss, sv = e1/ss, sl = e2/ss;
  float dav = Eav/(Sa*Sv), dal = Eal/(Sa*Sl), dvl = Evl/(Sv*Sl);
  float sav = (sa+sv)/(dav+0.5f);
  float sal = (sa+sl)/(dal+0.5f);
  float svl = (sv+sl)/(dvl+0.5f);
  float m2 = fmaxf(sav, fmaxf(sal, svl));
  float f0 = __expf(sav-m2), f1 = __expf(sal-m2), f2 = __expf(svl-m2);
  float s2 = f0 + f1 + f2;
  float wb0 = f0/s2, wb1 = f1/s2, wb2 = f2/s2;

  if(lane == 0){
    float* st = stats + (size_t)r*24;
    st[0]=sa; st[1]=sv; st[2]=sl;
    st[3]=wb0; st[4]=wb1; st[5]=wb2;
    st[6]=sav; st[7]=sal; st[8]=svl;
    st[9]=mA; st[10]=Sa; st[11]=mV; st[12]=Sv; st[13]=mL; st[14]=Sl;
    float* twr = tw + (size_t)r*12;
    twr[0]=sa; twr[1]=sv; twr[2]=sl; twr[3]=wb0; twr[4]=wb1; twr[5]=wb2;
  }
  u32* uniw = (u32*)(uniB + (size_t)r*DD);
  #pragma unroll
  for(int i = 0; i < 8; i++){
    int k2 = lane + i*64;
    float ux = (sa*a[i].x + sv*v[i].x + sl*l[i].x) * (1.0f/3.0f);
    float uy = (sa*a[i].y + sv*v[i].y + sl*l[i].y) * (1.0f/3.0f);
    uniw[k2] = pack2bf(ux, uy);
  }
}

// ---------- layer-1 MFMA GEMM: (3NB,1024) @ Wb1^T -> UV (3NB x 128 fp32) ----------
template<int FCAT>
__global__ __launch_bounds__(256) void kg1v3(
    const u16* __restrict__ src, const u16* __restrict__ Wb1,
    float* __restrict__ UV)
{
  __shared__ u16 Asm[2][64*64];   // 2 x 8KB
  int tid = threadIdx.x;
  int wv = tid >> 6, lane = tid & 63;
  int fr = lane & 15, kg = lane >> 4;
  int mb = blockIdx.x * 64;

  int r8 = lane >> 3, p = lane & 7;
  int sp = p ^ r8;
  int m0 = mb + (2*wv)*8 + r8;
  int m1 = mb + (2*wv+1)*8 + r8;
  size_t b0, b1;
  if(FCAT){
    int R0 = m0/3, R1 = m1/3;
    b0 = (size_t)R0*KF + (size_t)(1 + (m0 - 3*R0))*1024;
    b1 = (size_t)R1*KF + (size_t)(1 + (m1 - 3*R1))*1024;
  } else {
    b0 = (size_t)m0*1024;
    b1 = (size_t)m1*1024;
  }
  const u16* gsrc0 = src + b0 + sp*8;
  const u16* gsrc1 = src + b1 + sp*8;

  f32x4 acc[4][2];
  #pragma unroll
  for(int rf = 0; rf < 4; rf++)
    #pragma unroll
    for(int nf = 0; nf < 2; nf++) acc[rf][nf] = (f32x4){0.f,0.f,0.f,0.f};

  gll16(gsrc0, &Asm[0][(2*wv)*512]);
  gll16(gsrc1, &Asm[0][(2*wv+1)*512]);
  __syncthreads();

  int buf = 0;
  for(int ci = 0; ci < 16; ci++){
    int k0 = ci*64;
    if(ci < 15){
      gll16(gsrc0 + k0 + 64, &Asm[buf^1][(2*wv)*512]);
      gll16(gsrc1 + k0 + 64, &Asm[buf^1][(2*wv+1)*512]);
    }
    #pragma unroll
    for(int ks = 0; ks < 2; ks++){
      bf16x8 a[4];
      #pragma unroll
      for(int rf = 0; rf < 4; rf++){
        int row = rf*16 + fr;
        int slot = (ks*4 + kg) ^ (row & 7);
        a[rf] = *(const bf16x8*)&Asm[buf][row*64 + slot*8];
      }
      #pragma unroll
      for(int nf = 0; nf < 2; nf++){
        int col = wv*32 + nf*16 + fr;
        bf16x8 b = *(const bf16x8*)&Wb1[(size_t)col*1024 + k0 + ks*32 + kg*8];
        #pragma unroll
        for(int rf = 0; rf < 4; rf++)
          acc[rf][nf] = __builtin_amdgcn_mfma_f32_16x16x32_bf16(a[rf], b, acc[rf][nf], 0, 0, 0);
      }
    }
    __syncthreads();
    buf ^= 1;
  }

  #pragma unroll
  for(int rf = 0; rf < 4; rf++)
    #pragma unroll
    for(int nf = 0; nf < 2; nf++)
      #pragma unroll
      for(int q = 0; q < 4; q++)
        UV[(size_t)(mb + rf*16 + kg*4 + q)*128 + wv*32 + nf*16 + fr] = acc[rf][nf][q];
}

// ---------- layer-2 MFMA v5: t-build + MFMA + epilogue + fused y1 pass ----------
// block: 16 rows x 256 cols slab, 4 waves. grid (NB/16, 4).
// P==3 (!SUM): stores mid planes to Fcat, accumulates bimodal-sum y1 part.
// P==6 (SUM):  no Fcat store; accumulates tri y1 part.
template<int P, int SUM>
__global__ __launch_bounds__(256) void kL2v5(
    const float* __restrict__ UVA, const float* __restrict__ UVB,
    const u16* __restrict__ W2T, const u16* __restrict__ WpT,
    const float* __restrict__ b1, const float* __restrict__ b2,
    const float* __restrict__ stats, u16* __restrict__ Fcat,
    float* __restrict__ y1g)
{
  const int NO = SUM ? 1 : 4;          // Osm planes (mid: 3 + sum)
  __shared__ u16 Tsm[P][16][64];       // swizzled t fragments
  __shared__ u16 Osm[NO][16][264];     // padded output bounce
  __shared__ float stw[16][8];
  int tid = threadIdx.x;
  int wv = tid >> 6, lane = tid & 63;
  int fr = lane & 15, kg = lane >> 4;
  int Rb = blockIdx.x * 16;

  // ---- phase 1: t = lrelu0.2(U+V+b1) -> Tsm ----
  const int NG = P*16*8;
  for(int i = tid; i < NG; i += 256){
    int g = i & 7, r = (i >> 3) & 15, p = i >> 7;
    int R = Rb + r;
    int up, vp; const float* VBb;
    if(P == 3){
      up = (p == 2) ? 1 : 0;           // a1,a1,v1
      vp = (p == 0) ? 1 : 2;           // v1,l1,l1
      VBb = UVA;
    } else {
      up = (0x210200 >> (p*4)) & 15;   // a_v,a_v,v_l,a_v,a_l,v_l
      vp = (0x012112 >> (p*4)) & 15;   // v_l,a_l,a_l,l1,v1,a1
      VBb = (p < 3) ? UVA : UVB;
    }
    const float* Up = UVA + (size_t)(3*R + up)*128 + g*8;
    const float* Vp = VBb + (size_t)(3*R + vp)*128 + 64 + g*8;
    float4 u0 = *(const float4*)Up, u1 = *(const float4*)(Up+4);
    float4 v0 = *(const float4*)Vp, v1 = *(const float4*)(Vp+4);
    float4 bb0 = *(const float4*)(b1 + g*8), bb1 = *(const float4*)(b1 + g*8 + 4);
    float t[8] = {u0.x+v0.x+bb0.x, u0.y+v0.y+bb0.y, u0.z+v0.z+bb0.z, u0.w+v0.w+bb0.w,
                  u1.x+v1.x+bb1.x, u1.y+v1.y+bb1.y, u1.z+v1.z+bb1.z, u1.w+v1.w+bb1.w};
    bf16x8 o;
    #pragma unroll
    for(int j = 0; j < 8; j++){
      float tv = t[j] > 0.f ? t[j] : 0.2f*t[j];
      o[j] = (short)f2bf_tr(tv);
    }
    *(bf16x8*)&Tsm[p][r][(g ^ (r & 7))*8] = o;
  }
  if(tid < 16*P){
    int r = tid / P, p = tid - r*P;
    stw[r][p] = stats[(size_t)(Rb + r)*24 + (SUM ? 15 : 3) + p];
  }
  __syncthreads();

  // ---- phase 2: layer-2 MFMA ----
  f32x4 acc[P][4];
  #pragma unroll
  for(int p = 0; p < P; p++)
    #pragma unroll
    for(int cf = 0; cf < 4; cf++) acc[p][cf] = (f32x4){0.f,0.f,0.f,0.f};

  #pragma unroll
  for(int ks = 0; ks < 2; ks++){
    bf16x8 a[P];
    #pragma unroll
    for(int p = 0; p < P; p++)
      a[p] = *(const bf16x8*)&Tsm[p][fr][(((ks<<2)+kg) ^ (fr & 7))*8];
    #pragma unroll
    for(int cf = 0; cf < 4; cf++){
      bf16x8 b = *(const bf16x8*)&W2T[(size_t)(blockIdx.y*256 + wv*64 + cf*16 + fr)*64
                                      + ks*32 + kg*8];
      #pragma unroll
      for(int p = 0; p < P; p++)
        acc[p][cf] = __builtin_amdgcn_mfma_f32_16x16x32_bf16(a[p], b, acc[p][cf], 0, 0, 0);
    }
  }

  // ---- phase 3: epilogue -> Osm ----
  #pragma unroll
  for(int q = 0; q < 4; q++){
    int row = kg*4 + q;
    #pragma unroll
    for(int cf = 0; cf < 4; cf++){
      int cloc = wv*64 + cf*16 + fr;
      float b2c = b2[blockIdx.y*256 + cloc];
      if(SUM){
        float s = 0.f;
        #pragma unroll
        for(int p = 0; p < P; p++){
          float g = stw[row][p] * fast_tanh(acc[p][cf][q] + b2c);
          s += g > 0.f ? g : 0.01f*g;
        }
        Osm[0][row][cloc] = f2bf_tr(s * (1.0f/6.0f));
      } else {
        float sm = 0.f;
        #pragma unroll
        for(int p = 0; p < P; p++){
          float g = stw[row][p] * fast_tanh(acc[p][cf][q] + b2c);
          float val = g > 0.f ? g : 0.01f*g;
          Osm[p][row][cloc] = f2bf(val);
          sm += val;
        }
        Osm[3][row][cloc] = f2bf_tr(sm);   // Wp mid slice carries the /3
      }
    }
  }
  __syncthreads();

  // ---- phase 4a: coalesced mid store-out (P==3 only) ----
  if(!SUM){
    int orow = tid >> 4, oc16 = (tid & 15) * 16;
    #pragma unroll
    for(int p = 0; p < 3; p++){
      bf16x8 o0 = *(const bf16x8*)&Osm[p][orow][oc16];
      bf16x8 o1 = *(const bf16x8*)&Osm[p][orow][oc16 + 8];
      size_t off = (size_t)(Rb + orow)*KF + (size_t)(1+p)*1024 + blockIdx.y*256 + oc16;
      *(bf16x8*)&Fcat[off]     = o0;
      *(bf16x8*)&Fcat[off + 8] = o1;
    }
  }

  // ---- phase 4b: fused y1 contribution: Osm[NO-1] @ WpT slice -> atomicAdd ----
  {
    size_t kbase = (SUM ? 4096 : 1024) + (size_t)blockIdx.y*256;
    const u16* bptr = WpT + (size_t)(wv*16 + fr)*KF + kbase + kg*8;
    f32x4 accy = (f32x4){0.f,0.f,0.f,0.f};
    #pragma unroll
    for(int kq = 0; kq < 4; kq++)
      #pragma unroll
      for(int ks = 0; ks < 2; ks++){
        bf16x8 a = *(const bf16x8*)&Osm[NO-1][fr][kq*64 + ks*32 + kg*8];
        bf16x8 b = *(const bf16x8*)(bptr + kq*64 + ks*32);
        accy = __builtin_amdgcn_mfma_f32_16x16x32_bf16(a, b, accy, 0, 0, 0);
      }
    #pragma unroll
    for(int q = 0; q < 4; q++)
      atomicAdd(&y1g[(size_t)(Rb + kg*4 + q)*64 + wv*16 + fr], accy[q]);
  }
}

// ---------- K3s v2: no-max single-pass cross-dot stats -> w_tri ----------
__global__ __launch_bounds__(256) void k3s_v2(
    const u16* __restrict__ Fcat, const u16* __restrict__ xb,
    float* __restrict__ stats, float* __restrict__ tw)
{
  int wave = threadIdx.x >> 6, lane = threadIdx.x & 63;
  int r = blockIdx.x * 4 + wave;
  const u32* pv = (const u32*)(Fcat + (size_t)r*KF + 1024);
  const u32* xv = (const u32*)(xb + (size_t)3*r*DD);

  float* st = stats + (size_t)r*24;
  float sa=st[0], sv=st[1], sl=st[2];
  float sav=st[6], sal=st[7], svl=st[8];
  float mA=st[9], Sa=st[10], mV=st[11], Sv=st[12], mL=st[13], Sl=st[14];

  // av/al/vl in [-0.01, 1] -> exp bounded by e; no max subtraction needed
  // (max factors cancel in every d-ratio).
  float Savv=0.f,Sall=0.f,Svll=0.f,E1=0.f,E2=0.f,E3=0.f,E4=0.f,E5=0.f,E6=0.f;
  #pragma unroll
  for(int i = 0; i < 8; i++){
    int k2 = lane + i*64;
    u32 wa = pv[k2], wb = pv[512+k2], wc = pv[1024+k2];
    u32 xa = xv[k2], xvv = xv[512+k2], xl = xv[1024+k2];
    float eavx = __expf(bf2f((u16)wa)),      eavy = __expf(bf2f((u16)(wa>>16)));
    float ealx = __expf(bf2f((u16)wb)),      ealy = __expf(bf2f((u16)(wb>>16)));
    float evlx = __expf(bf2f((u16)wc)),      evly = __expf(bf2f((u16)(wc>>16)));
    float eax  = __expf(bf2f((u16)xa)-mA),   eay  = __expf(bf2f((u16)(xa>>16))-mA);
    float evx  = __expf(bf2f((u16)xvv)-mV),  evy  = __expf(bf2f((u16)(xvv>>16))-mV);
    float elx  = __expf(bf2f((u16)xl)-mL),   ely  = __expf(bf2f((u16)(xl>>16))-mL);
    Savv += eavx+eavy; Sall += ealx+ealy; Svll += evlx+evly;
    E1 += eavx*evlx + eavy*evly; E2 += eavx*ealx + eavy*ealy; E3 += ealx*evlx + ealy*evly;
    E4 += eavx*elx + eavy*ely;   E5 += ealx*evx + ealy*evy;   E6 += evlx*eax + evly*eay;
  }
  Savv = wredsum(Savv); Sall = wredsum(Sall); Svll = wredsum(Svll);
  E1 = wredsum(E1); E2 = wredsum(E2); E3 = wredsum(E3);
  E4 = wredsum(E4); E5 = wredsum(E5); E6 = wredsum(E6);

  float d1 = E1/(Savv*Svll), d2 = E2/(Savv*Sall), d3 = E3/(Sall*Svll);
  float d4 = E4/(Savv*Sl),   d5 = E5/(Sall*Sv),   d6 = E6/(Svll*Sa);
  float t0 = (sav+svl)/(d1+0.5f);
  float t1 = (sav+sal)/(d2+0.5f);
  float t2 = (sal+svl)/(d3+0.5f);
  float t3 = (sav+sl)/(d4+0.5f);
  float t4 = (sal+sv)/(d5+0.5f);
  float t5 = (sa+svl)/(d6+0.5f);
  float mx = fmaxf(fmaxf(fmaxf(t0,t1),fmaxf(t2,t3)),fmaxf(t4,t5));
  float g0=__expf(t0-mx),g1=__expf(t1-mx),g2=__expf(t2-mx);
  float g3=__expf(t3-mx),g4=__expf(t4-mx),g5=__expf(t5-mx);
  float gs = g0+g1+g2+g3+g4+g5;
  if(lane == 0){
    float wt[6] = {g0/gs,g1/gs,g2/gs,g3/gs,g4/gs,g5/gs};
    float* twr = tw + (size_t)r*12;
    #pragma unroll
    for(int p = 0; p < 6; p++){ st[15+p] = wt[p]; twr[6+p] = wt[p]; }
  }
}

// ---------- K6 v5: uni GEMM (K=1024) + y1g + MLP tail ----------
// M-tile 32, 256 thr / 4 waves; A = uniB (dense rows), 128-wide K chunks.
__global__ __launch_bounds__(256) void k6v5(
    const u16* __restrict__ uniB, const u16* __restrict__ WpT,
    const float* __restrict__ y1g, const float* __restrict__ bp,
    const float* __restrict__ l2W, const float* __restrict__ l2b,
    const float* __restrict__ l3W, const float* __restrict__ l3b,
    float* __restrict__ y2out)
{
  __shared__ __align__(16) char smem[37952];
  u16*  Asm = (u16*)smem;                            // [2][4096] = 16 KB
  float* W2s = (float*)(smem + 16384);               // [50][64]
  float* W3s = (float*)(smem + 16384 + 12800);       // [50][8]
  float* Ys  = (float*)smem;                         // [32][56] aliases Asm
  float* Ys2 = (float*)(smem + 16384 + 12800 + 1600);// [32][56]

  int tid = threadIdx.x;
  int wv = tid >> 6, lane = tid & 63;
  int fr = lane & 15, kg = lane >> 4;
  int rb = blockIdx.x * 32;

  for(int t = tid; t < 3200; t += 256){
    int c = t & 63;
    W2s[t] = (c < 50) ? l2W[(t >> 6)*50 + c] : 0.f;
  }
  for(int t = tid; t < 400; t += 256) W3s[t] = l3W[t];

  int r8 = lane >> 3, pp = lane & 7;
  int sp = pp ^ r8;
  const u16* gsrc = uniB + (size_t)(rb + wv*8 + r8)*DD + sp*8;
  const u16* bptr = WpT  + (size_t)(wv*16 + fr)*KF + kg*8;   // uni slice k<1024

  f32x4 acc[2];
  acc[0] = (f32x4){0.f,0.f,0.f,0.f};
  acc[1] = (f32x4){0.f,0.f,0.f,0.f};

  gll16(gsrc,      &Asm[wv*1024]);
  gll16(gsrc + 64, &Asm[wv*1024 + 512]);
  __syncthreads();

  int buf = 0;
  for(int ci = 0; ci < 8; ci++){
    int k0 = ci*128;
    if(ci < 7){
      gll16(gsrc + k0 + 128, &Asm[(buf^1)*4096 + wv*1024]);
      gll16(gsrc + k0 + 192, &Asm[(buf^1)*4096 + wv*1024 + 512]);
    }
    #pragma unroll
    for(int kh = 0; kh < 2; kh++){
      #pragma unroll
      for(int ks = 0; ks < 2; ks++){
        bf16x8 b = *(const bf16x8*)(bptr + k0 + kh*64 + ks*32);
        #pragma unroll
        for(int rf = 0; rf < 2; rf++){
          int row = rf*16 + fr;
          int slot = ((ks<<2) + kg) ^ (row & 7);
          bf16x8 a = *(const bf16x8*)&Asm[buf*4096 + (row>>3)*1024 + kh*512
                                          + (row & 7)*64 + slot*8];
          acc[rf] = __builtin_amdgcn_mfma_f32_16x16x32_bf16(a, b, acc[rf], 0, 0, 0);
        }
      }
    }
    __syncthreads();
    buf ^= 1;
  }

  // epilogue: Ys = tanh(acc + y1g + bp)
  {
    int col = wv*16 + fr;
    float bpc = bp[col];
    #pragma unroll
    for(int rf = 0; rf < 2; rf++)
      #pragma unroll
      for(int q = 0; q < 4; q++){
        int row = rf*16 + kg*4 + q;
        if(col < 50){
          float z = acc[rf][q] + y1g[(size_t)(rb + row)*64 + col] + bpc;
          Ys[row*56 + col] = fast_tanh(z);
        }
      }
  }
  __syncthreads();

  // stage 2: Ys(32x50) @ W2 -> tanh -> Ys2
  {
    int r = tid >> 3, cg = (tid & 7) * 7;
    float a2[7] = {0,0,0,0,0,0,0};
    for(int k = 0; k < 50; k++){
      float yv = Ys[r*56 + k];
      #pragma unroll
      for(int c = 0; c < 7; c++) a2[c] = fmaf(yv, W2s[k*64 + cg + c], a2[c]);
    }
    #pragma unroll
    for(int c = 0; c < 7; c++){
      int cc = cg + c;
      if(cc < 50) Ys2[r*56 + cc] = fast_tanh(a2[c] + l2b[cc]);
    }
  }
  __syncthreads();

  // stage 3: Ys2(32x50) @ W3 + b3, softmax over 8
  {
    int r = tid >> 3, c = tid & 7;
    float z = l3b[c];
    for(int k = 0; k < 50; k++) z = fmaf(Ys2[r*56 + k], W3s[k*8 + c], z);
    float m = z;
    m = fmaxf(m, __shfl_xor(m, 1));
    m = fmaxf(m, __shfl_xor(m, 2));
    m = fmaxf(m, __shfl_xor(m, 4));
    float e = __expf(z - m);
    float s = e;
    s += __shfl_xor(s, 1); s += __shfl_xor(s, 2); s += __shfl_xor(s, 4);
    y2out[(size_t)(rb + r)*8 + c] = e / s;
  }
}

// ---------- launch ----------
extern "C" void kernel_launch(void* const* d_in, const int* in_sizes, int n_in,
                              void* d_out, int out_size, void* d_ws, size_t ws_size,
                              hipStream_t stream)
{
  (void)in_sizes; (void)n_in; (void)out_size; (void)ws_size;
  const float* x    = (const float*)d_in[0];
  const float* attW = (const float*)d_in[1];
  const float* attb = (const float*)d_in[2];
  const float* gfW1 = (const float*)d_in[3];
  const float* gfb1 = (const float*)d_in[4];
  const float* gfW2 = (const float*)d_in[5];
  const float* gfb2 = (const float*)d_in[6];
  const float* bng  = (const float*)d_in[7];
  const float* bnb  = (const float*)d_in[8];
  const float* l1W  = (const float*)d_in[9];
  const float* l1b  = (const float*)d_in[10];
  const float* l2W  = (const float*)d_in[11];
  const float* l2b  = (const float*)d_in[12];
  const float* l3W  = (const float*)d_in[13];
  const float* l3b  = (const float*)d_in[14];

  float* out = (float*)d_out;
  float* tw  = out + (size_t)NB*8;

  // workspace layout (~382 MB)
  float* ws    = (float*)d_ws;
  float* stats = ws;                               // NB*24 f32
  float* UV1   = stats + (size_t)NB*24;            // 3*NB*128 f32
  float* UV2   = UV1 + (size_t)3*NB*128;           // 3*NB*128 f32
  float* bp    = UV2 + (size_t)3*NB*128;           // 64 f32
  float* y1g   = bp + 64;                          // NB*64 f32
  u16* WpT     = (u16*)(y1g + (size_t)NB*64);      // 64*KF bf16
  u16* Wb1     = WpT + (size_t)64*KF;              // 128*1024 bf16
  u16* W2T     = Wb1 + (size_t)128*1024;           // 1024*64 bf16
  u16* Fcat    = W2T + (size_t)1024*64;            // NB*KF bf16 (mid planes used)
  u16* xb      = Fcat + (size_t)NB*KF;             // 3*NB*1024 bf16
  u16* uniB    = xb + (size_t)3*NB*DD;             // NB*1024 bf16

  kpre<<<dim3(768 + 1280 + 1024 + 1), dim3(256), 0, stream>>>(
      gfW1, gfW2, bng, bnb, l1W, l1b, Wb1, W2T, WpT, bp, y1g);
  k1_stats<<<dim3(NB/4), dim3(256), 0, stream>>>(x, attW, attb, stats, uniB, xb, tw);

  kg1v3<0><<<dim3(3*NB/64), dim3(256), 0, stream>>>(xb, Wb1, UV1);
  kL2v5<3,0><<<dim3(NB/16, 4), dim3(256), 0, stream>>>(UV1, UV1, W2T, WpT,
                                                       gfb1, gfb2, stats, Fcat, y1g);
  k3s_v2<<<dim3(NB/4), dim3(256), 0, stream>>>(Fcat, xb, stats, tw);
  kg1v3<1><<<dim3(3*NB/64), dim3(256), 0, stream>>>(Fcat, Wb1, UV2);
  kL2v5<6,1><<<dim3(NB/16, 4), dim3(256), 0, stream>>>(UV2, UV1, W2T, WpT,
                                                       gfb1, gfb2, stats, Fcat, y1g);
  k6v5<<<dim3(NB/32), dim3(256), 0, stream>>>(uniB, WpT, y1g, bp,
                                              l2W, l2b, l3W, l3b, out);
}